// Round 9
// baseline (1072.549 us; speedup 1.0000x reference)
//
#include <hip/hip_runtime.h>

#define E_TOTAL   500000
#define NN        50000
#define ND        128
#define ED        128
#define HID       256
#define IND       384   /* 2*ND + ED */
#define EB        64    /* edges per tile */
#define TPB       4     /* tiles per block */
#define NBLOCKS   ((E_TOTAL + EB * TPB - 1) / (EB * TPB))

typedef float  f32x4  __attribute__((ext_vector_type(4)));
typedef short  bf16x8 __attribute__((ext_vector_type(8)));

__device__ __forceinline__ unsigned short f2bf(float f) {
    unsigned int u = __float_as_uint(f);
    u += 0x7FFFu + ((u >> 16) & 1u);   // RNE
    return (unsigned short)(u >> 16);
}
__device__ __forceinline__ float bf2f(unsigned short h) {
    return __uint_as_float(((unsigned int)h) << 16);
}

// ---------------- prep: both weights fp32 -> bf16 transposed ----------------
__global__ void prep_weights(const float* __restrict__ w1, const float* __restrict__ w2,
                             unsigned short* __restrict__ w1t, unsigned short* __restrict__ w2t) {
    int i = blockIdx.x * blockDim.x + threadIdx.x;
    if (i < IND * HID) {
        int k = i / HID, n = i % HID;
        w1t[n * IND + k] = f2bf(w1[i]);          // W1T[n][k] = W1[k][n]
    } else if (i < IND * HID + HID * ED) {
        int q = i - IND * HID;
        int k = q / ED, n = q % ED;
        w2t[n * HID + k] = f2bf(w2[q]);          // W2T[n][k] = W2[k][n]
    }
}

// ---------------- prep: per-node partial products ----------------
// Psrc[n][:] = nodes[n] @ W1[0:128, :] + b1   (bf16, 50000x256)
// Pdst[n][:] = nodes[n] @ W1[128:256, :]      (bf16, 50000x256)
__global__ __launch_bounds__(256, 2)
void prep_ptab(const float* __restrict__ nf,
               const unsigned short* __restrict__ w1t,
               const float* __restrict__ b1,
               unsigned short* __restrict__ Psrc,
               unsigned short* __restrict__ Pdst) {
    __shared__ unsigned short An[64 * ND];   // 16 KB swizzled
    const int tid  = threadIdx.x;
    const int base = blockIdx.x * 64;
    const int lane = tid & 63;
    const int w    = tid >> 6;
    const int l15  = lane & 15;
    const int lhi  = lane >> 4;

    #pragma unroll
    for (int it = 0; it < 4; ++it) {
        int item = tid + it * 256;          // 0..1023
        int row = item >> 4, cc = item & 15;
        int nidx = base + row;
        if (nidx >= NN) nidx = NN - 1;
        const float* p = nf + (size_t)nidx * ND + cc * 8;
        float4 f0 = *(const float4*)p;
        float4 f1 = *(const float4*)(p + 4);
        bf16x8 val;
        val[0] = (short)f2bf(f0.x); val[1] = (short)f2bf(f0.y);
        val[2] = (short)f2bf(f0.z); val[3] = (short)f2bf(f0.w);
        val[4] = (short)f2bf(f1.x); val[5] = (short)f2bf(f1.y);
        val[6] = (short)f2bf(f1.z); val[7] = (short)f2bf(f1.w);
        *(bf16x8*)(An + row * ND + ((cc * 8) ^ ((row & 7) * 8))) = val;
    }
    __syncthreads();

    f32x4 accs[4][4], accd[4][4];
    #pragma unroll
    for (int mt = 0; mt < 4; ++mt)
        #pragma unroll
        for (int nt = 0; nt < 4; ++nt) { accs[mt][nt] = (f32x4)0.0f; accd[mt][nt] = (f32x4)0.0f; }

    #pragma unroll
    for (int ks = 0; ks < 4; ++ks) {
        int c0 = ks * 32 + lhi * 8;
        bf16x8 a[4];
        #pragma unroll
        for (int mt = 0; mt < 4; ++mt) {
            int row = mt * 16 + l15;
            a[mt] = *(const bf16x8*)(An + row * ND + (c0 ^ ((row & 7) * 8)));
        }
        #pragma unroll
        for (int nt = 0; nt < 4; ++nt) {
            int n = w * 64 + nt * 16 + l15;
            bf16x8 bs = *(const bf16x8*)(w1t + (size_t)n * IND + c0);
            bf16x8 bd = *(const bf16x8*)(w1t + (size_t)n * IND + 128 + c0);
            #pragma unroll
            for (int mt = 0; mt < 4; ++mt) {
                accs[mt][nt] = __builtin_amdgcn_mfma_f32_16x16x32_bf16(a[mt], bs, accs[mt][nt], 0, 0, 0);
                accd[mt][nt] = __builtin_amdgcn_mfma_f32_16x16x32_bf16(a[mt], bd, accd[mt][nt], 0, 0, 0);
            }
        }
    }

    #pragma unroll
    for (int nt = 0; nt < 4; ++nt) {
        int col = w * 64 + nt * 16 + l15;
        float bias = b1[col];
        #pragma unroll
        for (int mt = 0; mt < 4; ++mt) {
            #pragma unroll
            for (int r = 0; r < 4; ++r) {
                int row = mt * 16 + lhi * 4 + r;
                int nidx = base + row;
                if (nidx < NN) {
                    size_t off = (size_t)nidx * HID + col;
                    Psrc[off] = f2bf(accs[mt][nt][r] + bias);
                    Pdst[off] = f2bf(accd[mt][nt][r]);
                }
            }
        }
    }
}

// ---------------- main fused kernel: R3 skeleton + T14 async-STAGE pipeline ----
// 256 threads (4 waves), LDS 48 KB (Ae 16K + Hs 32K) -> 3 blocks/CU.
// Each block runs TPB=4 consecutive 64-edge tiles. Tile t+1's gather loads
// (P-rows + edgef) are ISSUED into registers before tile t's compute, so the
// random-read latency hides under GEMM1+merge+GEMM2+epilogue; the register
// data is WRITTEN to LDS after the tile's last reader barrier.
__global__ __launch_bounds__(256, 3)
void edge_mlp(const float* __restrict__ edgef,
              const int* __restrict__ eidx,
              const unsigned short* __restrict__ Psrc,
              const unsigned short* __restrict__ Pdst,
              const unsigned short* __restrict__ w1t,
              const unsigned short* __restrict__ w2t,
              const float* __restrict__ b2,
              float* __restrict__ out) {
    __shared__ unsigned short Ae[EB * ND];    // 16 KB
    __shared__ unsigned short Hs[EB * HID];   // 32 KB

    const int tid  = threadIdx.x;
    const int lane = tid & 63;
    const int w    = tid >> 6;       // 0..3
    const int l15  = lane & 15;
    const int lhi  = lane >> 4;
    const int* srcI = eidx;
    const int* dstI = eidx + E_TOTAL;
    const int block0 = blockIdx.x * (EB * TPB);

    // staged registers for the next tile
    bf16x8 vs[8], vd[8];             // P-row chunks (64 VGPR)
    float4 ae0[4], ae1[4];           // edgef chunks  (32 VGPR)

    // ---------- STAGE_ISSUE: launch gather loads for tile at tbase ----------
    auto STAGE_ISSUE = [&](int tbase) {
        #pragma unroll
        for (int it = 0; it < 8; ++it) {
            int item = tid + it * 256;        // 0..2047 = 64 rows x 32 chunks
            int row = item >> 5, cc = item & 31;
            int e = tbase + row;
            int el = e < E_TOTAL ? e : E_TOTAL - 1;
            int s = srcI[el], d = dstI[el];
            vs[it] = *(const bf16x8*)(Psrc + (size_t)s * HID + cc * 8);
            vd[it] = *(const bf16x8*)(Pdst + (size_t)d * HID + cc * 8);
        }
        #pragma unroll
        for (int it = 0; it < 4; ++it) {
            int item = tid + it * 256;        // 0..1023 = 64 rows x 16 chunks
            int row = item >> 4, cc = item & 15;
            int e = tbase + row;
            int el = e < E_TOTAL ? e : E_TOTAL - 1;
            const float* p = edgef + (size_t)el * ED + cc * 8;
            ae0[it] = *(const float4*)p;
            ae1[it] = *(const float4*)(p + 4);
        }
    };

    // ---------- STAGE_WRITE: convert staged regs -> LDS ----------
    auto STAGE_WRITE = [&]() {
        #pragma unroll
        for (int it = 0; it < 8; ++it) {
            int item = tid + it * 256;
            int row = item >> 5, cc = item & 31;
            bf16x8 o;
            #pragma unroll
            for (int j = 0; j < 8; ++j)
                o[j] = (short)f2bf(bf2f((unsigned short)vs[it][j]) + bf2f((unsigned short)vd[it][j]));
            *(bf16x8*)(Hs + row * HID + ((cc * 8) ^ ((row & 7) * 8))) = o;
        }
        #pragma unroll
        for (int it = 0; it < 4; ++it) {
            int item = tid + it * 256;
            int row = item >> 4, cc = item & 15;
            bf16x8 val;
            val[0] = (short)f2bf(ae0[it].x); val[1] = (short)f2bf(ae0[it].y);
            val[2] = (short)f2bf(ae0[it].z); val[3] = (short)f2bf(ae0[it].w);
            val[4] = (short)f2bf(ae1[it].x); val[5] = (short)f2bf(ae1[it].y);
            val[6] = (short)f2bf(ae1[it].z); val[7] = (short)f2bf(ae1[it].w);
            *(bf16x8*)(Ae + row * ND + ((cc * 8) ^ ((row & 7) * 8))) = val;
        }
    };

    // ---------- prologue: stage tile 0 ----------
    STAGE_ISSUE(block0);
    STAGE_WRITE();
    __syncthreads();

    for (int tp = 0; tp < TPB; ++tp) {
        const int base = block0 + tp * EB;

        // ---- issue next tile's gathers: latency hides under this tile ----
        if (tp + 1 < TPB) STAGE_ISSUE(base + EB);

        // ---- GEMM1: acc1(64x256) = Ae(64x128) @ W1[256:384,:] ----
        f32x4 acc1[4][4];
        #pragma unroll
        for (int mt = 0; mt < 4; ++mt)
            #pragma unroll
            for (int nt = 0; nt < 4; ++nt)
                acc1[mt][nt] = (f32x4)0.0f;

        #pragma unroll
        for (int ks = 0; ks < 4; ++ks) {
            int c0 = ks * 32 + lhi * 8;
            bf16x8 a[4];
            #pragma unroll
            for (int mt = 0; mt < 4; ++mt) {
                int row = mt * 16 + l15;
                a[mt] = *(const bf16x8*)(Ae + row * ND + (c0 ^ ((row & 7) * 8)));
            }
            #pragma unroll
            for (int nt = 0; nt < 4; ++nt) {
                int n = w * 64 + nt * 16 + l15;
                bf16x8 b = *(const bf16x8*)(w1t + (size_t)n * IND + 256 + c0);
                #pragma unroll
                for (int mt = 0; mt < 4; ++mt)
                    acc1[mt][nt] = __builtin_amdgcn_mfma_f32_16x16x32_bf16(a[mt], b, acc1[mt][nt], 0, 0, 0);
            }
        }

        // ---- merge: Hs = relu(acc1 + Hs) in place (b1 folded in Psrc) ----
        #pragma unroll
        for (int nt = 0; nt < 4; ++nt) {
            int col = w * 64 + nt * 16 + l15;
            #pragma unroll
            for (int mt = 0; mt < 4; ++mt) {
                #pragma unroll
                for (int r = 0; r < 4; ++r) {
                    int row = mt * 16 + lhi * 4 + r;
                    int idx = row * HID + (col ^ ((row & 7) * 8));
                    float v = acc1[mt][nt][r] + bf2f(Hs[idx]);
                    v = v > 0.0f ? v : 0.0f;
                    Hs[idx] = f2bf(v);
                }
            }
        }
        __syncthreads();

        // ---- GEMM2: U(64x128) = Hs(64x256) @ W2 ----
        f32x4 acc2[4][2];
        #pragma unroll
        for (int mt = 0; mt < 4; ++mt)
            #pragma unroll
            for (int nt = 0; nt < 2; ++nt)
                acc2[mt][nt] = (f32x4)0.0f;

        #pragma unroll
        for (int ks = 0; ks < 8; ++ks) {
            int c0 = ks * 32 + lhi * 8;
            bf16x8 a[4];
            #pragma unroll
            for (int mt = 0; mt < 4; ++mt) {
                int row = mt * 16 + l15;
                a[mt] = *(const bf16x8*)(Hs + row * HID + (c0 ^ ((row & 7) * 8)));
            }
            #pragma unroll
            for (int nt = 0; nt < 2; ++nt) {
                int n = w * 32 + nt * 16 + l15;
                bf16x8 b = *(const bf16x8*)(w2t + (size_t)n * HID + c0);
                #pragma unroll
                for (int mt = 0; mt < 4; ++mt)
                    acc2[mt][nt] = __builtin_amdgcn_mfma_f32_16x16x32_bf16(a[mt], b, acc2[mt][nt], 0, 0, 0);
            }
        }

        // ---- epilogue: out = Ae(bf16 edge) + update + b2 ----
        #pragma unroll
        for (int nt = 0; nt < 2; ++nt) {
            int col = w * 32 + nt * 16 + l15;
            float bias = b2[col];
            #pragma unroll
            for (int mt = 0; mt < 4; ++mt) {
                #pragma unroll
                for (int r = 0; r < 4; ++r) {
                    int row = mt * 16 + lhi * 4 + r;
                    int e = base + row;
                    if (e < E_TOTAL) {
                        float ev = bf2f(Ae[row * ND + (col ^ ((row & 7) * 8))]);
                        out[(size_t)e * ED + col] = ev + acc2[mt][nt][r] + bias;
                    }
                }
            }
        }

        // ---- rotate: overwrite LDS with the staged next tile ----
        if (tp + 1 < TPB) {
            __syncthreads();     // all waves done reading Ae/Hs of this tile
            STAGE_WRITE();       // waits (counted vmcnt) on the staged loads
            __syncthreads();
        }
    }
}

extern "C" void kernel_launch(void* const* d_in, const int* in_sizes, int n_in,
                              void* d_out, int out_size, void* d_ws, size_t ws_size,
                              hipStream_t stream) {
    const float* nf   = (const float*)d_in[0];
    const float* ef   = (const float*)d_in[1];
    const int*   eidx = (const int*)d_in[2];
    const float* W1   = (const float*)d_in[3];
    const float* b1   = (const float*)d_in[4];
    const float* W2   = (const float*)d_in[5];
    const float* b2   = (const float*)d_in[6];
    float* out = (float*)d_out;

    unsigned short* w1t  = (unsigned short*)d_ws;          // 192 KB
    unsigned short* w2t  = w1t + IND * HID;                // 64 KB
    unsigned short* Psrc = w2t + HID * ED;                 // 25.6 MB
    unsigned short* Pdst = Psrc + (size_t)NN * HID;        // 25.6 MB

    int wtotal = IND * HID + HID * ED;
    prep_weights<<<(wtotal + 255) / 256, 256, 0, stream>>>(W1, W2, w1t, w2t);
    prep_ptab<<<(NN + 63) / 64, 256, 0, stream>>>(nf, w1t, b1, Psrc, Pdst);
    edge_mlp<<<NBLOCKS, 256, 0, stream>>>(ef, eidx, Psrc, Pdst, w1t, w2t, b2, out);
}

// Round 10
// 299.698 us; speedup vs baseline: 3.5788x; 3.5788x over previous
//
#include <hip/hip_runtime.h>

#define E_TOTAL   500000
#define NN        50000
#define ND        128
#define ED        128
#define HID       256
#define IND       384   /* 2*ND + ED */
#define EB        64    /* edges per block */
#define NBLOCKS   ((E_TOTAL + EB - 1) / EB)

typedef float  f32x4  __attribute__((ext_vector_type(4)));
typedef short  bf16x8 __attribute__((ext_vector_type(8)));

__device__ __forceinline__ unsigned short f2bf(float f) {
    unsigned int u = __float_as_uint(f);
    u += 0x7FFFu + ((u >> 16) & 1u);   // RNE
    return (unsigned short)(u >> 16);
}
__device__ __forceinline__ float bf2f(unsigned short h) {
    return __uint_as_float(((unsigned int)h) << 16);
}

// ---------------- prep: both weights fp32 -> bf16 transposed ----------------
__global__ void prep_weights(const float* __restrict__ w1, const float* __restrict__ w2,
                             unsigned short* __restrict__ w1t, unsigned short* __restrict__ w2t) {
    int i = blockIdx.x * blockDim.x + threadIdx.x;
    if (i < IND * HID) {
        int k = i / HID, n = i % HID;
        w1t[n * IND + k] = f2bf(w1[i]);          // W1T[n][k] = W1[k][n]
    } else if (i < IND * HID + HID * ED) {
        int q = i - IND * HID;
        int k = q / ED, n = q % ED;
        w2t[n * HID + k] = f2bf(w2[q]);          // W2T[n][k] = W2[k][n]
    }
}

// ---------------- prep: per-node partial products ----------------
// Psrc[n][:] = nodes[n] @ W1[0:128, :] + b1   (bf16, 50000x256)
// Pdst[n][:] = nodes[n] @ W1[128:256, :]      (bf16, 50000x256)
__global__ __launch_bounds__(256, 2)
void prep_ptab(const float* __restrict__ nf,
               const unsigned short* __restrict__ w1t,
               const float* __restrict__ b1,
               unsigned short* __restrict__ Psrc,
               unsigned short* __restrict__ Pdst) {
    __shared__ unsigned short An[64 * ND];   // 16 KB swizzled
    const int tid  = threadIdx.x;
    const int base = blockIdx.x * 64;
    const int lane = tid & 63;
    const int w    = tid >> 6;
    const int l15  = lane & 15;
    const int lhi  = lane >> 4;

    #pragma unroll
    for (int it = 0; it < 4; ++it) {
        int item = tid + it * 256;          // 0..1023
        int row = item >> 4, cc = item & 15;
        int nidx = base + row;
        if (nidx >= NN) nidx = NN - 1;
        const float* p = nf + (size_t)nidx * ND + cc * 8;
        float4 f0 = *(const float4*)p;
        float4 f1 = *(const float4*)(p + 4);
        bf16x8 val;
        val[0] = (short)f2bf(f0.x); val[1] = (short)f2bf(f0.y);
        val[2] = (short)f2bf(f0.z); val[3] = (short)f2bf(f0.w);
        val[4] = (short)f2bf(f1.x); val[5] = (short)f2bf(f1.y);
        val[6] = (short)f2bf(f1.z); val[7] = (short)f2bf(f1.w);
        *(bf16x8*)(An + row * ND + ((cc * 8) ^ ((row & 7) * 8))) = val;
    }
    __syncthreads();

    f32x4 accs[4][4], accd[4][4];
    #pragma unroll
    for (int mt = 0; mt < 4; ++mt)
        #pragma unroll
        for (int nt = 0; nt < 4; ++nt) { accs[mt][nt] = (f32x4)0.0f; accd[mt][nt] = (f32x4)0.0f; }

    #pragma unroll
    for (int ks = 0; ks < 4; ++ks) {
        int c0 = ks * 32 + lhi * 8;
        bf16x8 a[4];
        #pragma unroll
        for (int mt = 0; mt < 4; ++mt) {
            int row = mt * 16 + l15;
            a[mt] = *(const bf16x8*)(An + row * ND + (c0 ^ ((row & 7) * 8)));
        }
        #pragma unroll
        for (int nt = 0; nt < 4; ++nt) {
            int n = w * 64 + nt * 16 + l15;
            bf16x8 bs = *(const bf16x8*)(w1t + (size_t)n * IND + c0);
            bf16x8 bd = *(const bf16x8*)(w1t + (size_t)n * IND + 128 + c0);
            #pragma unroll
            for (int mt = 0; mt < 4; ++mt) {
                accs[mt][nt] = __builtin_amdgcn_mfma_f32_16x16x32_bf16(a[mt], bs, accs[mt][nt], 0, 0, 0);
                accd[mt][nt] = __builtin_amdgcn_mfma_f32_16x16x32_bf16(a[mt], bd, accd[mt][nt], 0, 0, 0);
            }
        }
    }

    #pragma unroll
    for (int nt = 0; nt < 4; ++nt) {
        int col = w * 64 + nt * 16 + l15;
        float bias = b1[col];
        #pragma unroll
        for (int mt = 0; mt < 4; ++mt) {
            #pragma unroll
            for (int r = 0; r < 4; ++r) {
                int row = mt * 16 + lhi * 4 + r;
                int nidx = base + row;
                if (nidx < NN) {
                    size_t off = (size_t)nidx * HID + col;
                    Psrc[off] = f2bf(accs[mt][nt][r] + bias);
                    Pdst[off] = f2bf(accd[mt][nt][r]);
                }
            }
        }
    }
}

// ---------------- main fused kernel: R3 skeleton + deep-issue gather ----------
// 256 threads (4 waves), LDS 48 KB (Ae 16K + Hs 32K) -> 3 blocks/CU.
// Gather phase issues ALL 24 global loads (16 P-chunks + 8 edgef float4)
// before any consumption: ~24 outstanding loads/lane = 16 KB+ in flight per
// wave, saturating the random-read service rate. Staged registers die before
// the GEMM accumulators are created (no R9-style cross-phase spill).
__global__ __launch_bounds__(256, 3)
void edge_mlp(const float* __restrict__ edgef,
              const int* __restrict__ eidx,
              const unsigned short* __restrict__ Psrc,
              const unsigned short* __restrict__ Pdst,
              const unsigned short* __restrict__ w1t,
              const unsigned short* __restrict__ w2t,
              const float* __restrict__ b2,
              float* __restrict__ out) {
    __shared__ unsigned short Ae[EB * ND];    // 16 KB
    __shared__ unsigned short Hs[EB * HID];   // 32 KB

    const int tid  = threadIdx.x;
    const int base = blockIdx.x * EB;
    const int lane = tid & 63;
    const int w    = tid >> 6;
    const int l15  = lane & 15;
    const int lhi  = lane >> 4;
    const int* srcI = eidx;
    const int* dstI = eidx + E_TOTAL;

    // ================= deep-issue gather =================
    {
        bf16x8 vs[8], vd[8];         // 64 VGPR staged P-chunks
        float4 e0[4], e1[4];         // 32 VGPR staged edgef

        // ---- issue ALL loads first (24 outstanding per lane) ----
        #pragma unroll
        for (int it = 0; it < 8; ++it) {
            int item = tid + it * 256;        // 0..2047 = 64 rows x 32 chunks
            int row = item >> 5, cc = item & 31;
            int e = base + row;
            int el = e < E_TOTAL ? e : E_TOTAL - 1;
            int s = srcI[el], d = dstI[el];
            vs[it] = *(const bf16x8*)(Psrc + (size_t)s * HID + cc * 8);
            vd[it] = *(const bf16x8*)(Pdst + (size_t)d * HID + cc * 8);
        }
        #pragma unroll
        for (int it = 0; it < 4; ++it) {
            int item = tid + it * 256;        // 0..1023 = 64 rows x 16 chunks
            int row = item >> 4, cc = item & 15;
            int e = base + row;
            int el = e < E_TOTAL ? e : E_TOTAL - 1;
            const float* p = edgef + (size_t)el * ED + cc * 8;
            e0[it] = *(const float4*)p;
            e1[it] = *(const float4*)(p + 4);
        }

        // ---- consume in issue order (counted waitcnts keep tail in flight) ----
        #pragma unroll
        for (int it = 0; it < 8; ++it) {
            int item = tid + it * 256;
            int row = item >> 5, cc = item & 31;
            bf16x8 o;
            #pragma unroll
            for (int j = 0; j < 8; ++j)
                o[j] = (short)f2bf(bf2f((unsigned short)vs[it][j]) + bf2f((unsigned short)vd[it][j]));
            *(bf16x8*)(Hs + row * HID + ((cc * 8) ^ ((row & 7) * 8))) = o;
        }
        #pragma unroll
        for (int it = 0; it < 4; ++it) {
            int item = tid + it * 256;
            int row = item >> 4, cc = item & 15;
            bf16x8 val;
            val[0] = (short)f2bf(e0[it].x); val[1] = (short)f2bf(e0[it].y);
            val[2] = (short)f2bf(e0[it].z); val[3] = (short)f2bf(e0[it].w);
            val[4] = (short)f2bf(e1[it].x); val[5] = (short)f2bf(e1[it].y);
            val[6] = (short)f2bf(e1[it].z); val[7] = (short)f2bf(e1[it].w);
            *(bf16x8*)(Ae + row * ND + ((cc * 8) ^ ((row & 7) * 8))) = val;
        }
    }
    __syncthreads();

    // ---- GEMM1: acc1(64x256) = Ae(64x128) @ W1[256:384,:] ----
    f32x4 acc1[4][4];
    #pragma unroll
    for (int mt = 0; mt < 4; ++mt)
        #pragma unroll
        for (int nt = 0; nt < 4; ++nt)
            acc1[mt][nt] = (f32x4)0.0f;

    #pragma unroll
    for (int ks = 0; ks < 4; ++ks) {
        int c0 = ks * 32 + lhi * 8;
        bf16x8 a[4];
        #pragma unroll
        for (int mt = 0; mt < 4; ++mt) {
            int row = mt * 16 + l15;
            a[mt] = *(const bf16x8*)(Ae + row * ND + (c0 ^ ((row & 7) * 8)));
        }
        #pragma unroll
        for (int nt = 0; nt < 4; ++nt) {
            int n = w * 64 + nt * 16 + l15;
            bf16x8 b = *(const bf16x8*)(w1t + (size_t)n * IND + 256 + c0);
            #pragma unroll
            for (int mt = 0; mt < 4; ++mt)
                acc1[mt][nt] = __builtin_amdgcn_mfma_f32_16x16x32_bf16(a[mt], b, acc1[mt][nt], 0, 0, 0);
        }
    }

    // ---- merge: Hs = relu(acc1 + Hs) in place (b1 folded in Psrc) ----
    #pragma unroll
    for (int nt = 0; nt < 4; ++nt) {
        int col = w * 64 + nt * 16 + l15;
        #pragma unroll
        for (int mt = 0; mt < 4; ++mt) {
            #pragma unroll
            for (int r = 0; r < 4; ++r) {
                int row = mt * 16 + lhi * 4 + r;
                int idx = row * HID + (col ^ ((row & 7) * 8));
                float v = acc1[mt][nt][r] + bf2f(Hs[idx]);
                v = v > 0.0f ? v : 0.0f;
                Hs[idx] = f2bf(v);
            }
        }
    }
    __syncthreads();

    // ---- GEMM2: U(64x128) = Hs(64x256) @ W2 ----
    f32x4 acc2[4][2];
    #pragma unroll
    for (int mt = 0; mt < 4; ++mt)
        #pragma unroll
        for (int nt = 0; nt < 2; ++nt)
            acc2[mt][nt] = (f32x4)0.0f;

    #pragma unroll
    for (int ks = 0; ks < 8; ++ks) {
        int c0 = ks * 32 + lhi * 8;
        bf16x8 a[4];
        #pragma unroll
        for (int mt = 0; mt < 4; ++mt) {
            int row = mt * 16 + l15;
            a[mt] = *(const bf16x8*)(Hs + row * HID + (c0 ^ ((row & 7) * 8)));
        }
        #pragma unroll
        for (int nt = 0; nt < 2; ++nt) {
            int n = w * 32 + nt * 16 + l15;
            bf16x8 b = *(const bf16x8*)(w2t + (size_t)n * HID + c0);
            #pragma unroll
            for (int mt = 0; mt < 4; ++mt)
                acc2[mt][nt] = __builtin_amdgcn_mfma_f32_16x16x32_bf16(a[mt], b, acc2[mt][nt], 0, 0, 0);
        }
    }

    // ---- epilogue: out = Ae(bf16 edge) + update + b2 ----
    #pragma unroll
    for (int nt = 0; nt < 2; ++nt) {
        int col = w * 32 + nt * 16 + l15;
        float bias = b2[col];
        #pragma unroll
        for (int mt = 0; mt < 4; ++mt) {
            #pragma unroll
            for (int r = 0; r < 4; ++r) {
                int row = mt * 16 + lhi * 4 + r;
                int e = base + row;
                if (e < E_TOTAL) {
                    float ev = bf2f(Ae[row * ND + (col ^ ((row & 7) * 8))]);
                    out[(size_t)e * ED + col] = ev + acc2[mt][nt][r] + bias;
                }
            }
        }
    }
}

extern "C" void kernel_launch(void* const* d_in, const int* in_sizes, int n_in,
                              void* d_out, int out_size, void* d_ws, size_t ws_size,
                              hipStream_t stream) {
    const float* nf   = (const float*)d_in[0];
    const float* ef   = (const float*)d_in[1];
    const int*   eidx = (const int*)d_in[2];
    const float* W1   = (const float*)d_in[3];
    const float* b1   = (const float*)d_in[4];
    const float* W2   = (const float*)d_in[5];
    const float* b2   = (const float*)d_in[6];
    float* out = (float*)d_out;

    unsigned short* w1t  = (unsigned short*)d_ws;          // 192 KB
    unsigned short* w2t  = w1t + IND * HID;                // 64 KB
    unsigned short* Psrc = w2t + HID * ED;                 // 25.6 MB
    unsigned short* Pdst = Psrc + (size_t)NN * HID;        // 25.6 MB

    int wtotal = IND * HID + HID * ED;
    prep_weights<<<(wtotal + 255) / 256, 256, 0, stream>>>(W1, W2, w1t, w2t);
    prep_ptab<<<(NN + 63) / 64, 256, 0, stream>>>(nf, w1t, b1, Psrc, Pdst);
    edge_mlp<<<NBLOCKS, 256, 0, stream>>>(ef, eidx, Psrc, Pdst, w1t, w2t, b2, out);
}